// Round 3
// baseline (203.174 us; speedup 1.0000x reference)
//
#include <hip/hip_runtime.h>
#include <math.h>

#define NN   2048
#define BB   16

// ws layout (float offsets)
#define WS_X0   0
#define WS_QT   65536
#define WS_KT   131072
#define WS_VT   196608
#define WS_PART 262144   // [32 slot][4 h][4 kslice][12]: o[8], ssum, pad
#define WS_GI   268800   // [16 edge][96]

__device__ __forceinline__ float sigmoidf_(float x) { return 1.0f / (1.0f + __expf(-x)); }
__device__ __forceinline__ float tanhf_(float x) {
    float ex = __expf(2.0f * x);
    return 1.0f - 2.0f / (ex + 1.0f);
}
__device__ __forceinline__ float dot4_(float4 a, float4 b) {
    return a.x*b.x + a.y*b.y + a.z*b.z + a.w*b.w;
}

// ---------------------------------------------------------------------------
// K1: blocks 0..255: x0 = nf@Wemb^T+b ; qkv = x0@Wqkv^T+b  (head-major q/k/v)
//     blocks 0..63 additionally copy memory -> out[16..]
//     block 256:     messages -> gi = msg@Wih^T + bih   (for the GRU scan)
// ---------------------------------------------------------------------------
__global__ __launch_bounds__(256) void k1_embed_qkv(
    const float* __restrict__ nf, const float* __restrict__ Wemb, const float* __restrict__ bemb,
    const float* __restrict__ Wqkv, const float* __restrict__ bqkv,
    const float* __restrict__ mem, const int* __restrict__ src, const int* __restrict__ dst,
    const float* __restrict__ ef,
    const float* __restrict__ Wm1, const float* __restrict__ bm1,
    const float* __restrict__ Wm2, const float* __restrict__ bm2,
    const float* __restrict__ Wih, const float* __restrict__ bih,
    float* __restrict__ ws, float* __restrict__ out)
{
    // node path LDS (stride 130: float2 rows, 2-way bank aliasing = free)
    __shared__ float We_s[32 * 130];
    __shared__ float nf_s[8 * 130];
    __shared__ float x0_s[8 * 33];
    __shared__ float Wq_s[96 * 33];
    // message path LDS
    __shared__ __align__(16) float Wm1_s[32 * 67];
    __shared__ float Wm2_s[32 * 33];
    __shared__ float Wih_s[96 * 33];
    __shared__ float min_s[16 * 67];
    __shared__ float mr_s[16 * 33];
    __shared__ float msg_s[16 * 33];

    const int t = threadIdx.x, bx = blockIdx.x;

    if (bx == 256) {
        // ---- message path ----
        for (int idx = t; idx < 536; idx += 256)  // Wm1: 2144 floats linear
            ((float4*)Wm1_s)[idx] = ((const float4*)Wm1)[idx];
        for (int idx = t; idx < 256; idx += 256) { // Wm2: 1024 floats -> stride 33
            float4 v = ((const float4*)Wm2)[idx];
            int o = idx >> 3, i = (idx & 7) * 4;
            Wm2_s[o * 33 + i] = v.x; Wm2_s[o * 33 + i + 1] = v.y;
            Wm2_s[o * 33 + i + 2] = v.z; Wm2_s[o * 33 + i + 3] = v.w;
        }
        for (int idx = t; idx < 768; idx += 256) { // Wih: 3072 floats -> stride 33
            float4 v = ((const float4*)Wih)[idx];
            int o = idx >> 3, i = (idx & 7) * 4;
            Wih_s[o * 33 + i] = v.x; Wih_s[o * 33 + i + 1] = v.y;
            Wih_s[o * 33 + i + 2] = v.z; Wih_s[o * 33 + i + 3] = v.w;
        }
        for (int idx = t; idx < 16 * 67; idx += 256) {
            int e = idx / 67, i = idx - e * 67;
            float v;
            if (i < 32)      v = mem[src[e] * 32 + i];
            else if (i < 64) v = mem[dst[e] * 32 + (i - 32)];
            else             v = ef[e * 3 + (i - 64)];
            min_s[idx] = v;
        }
        __syncthreads();
        {
            int o = t & 31, e0 = t >> 5;
            for (int p = 0; p < 2; ++p) {
                int e = e0 + p * 8;
                float acc = bm1[o];
                for (int i = 0; i < 67; ++i) acc += Wm1_s[o * 67 + i] * min_s[e * 67 + i];
                mr_s[e * 33 + o] = fmaxf(acc, 0.f);
            }
        }
        __syncthreads();
        {
            int o = t & 31, e0 = t >> 5;
            for (int p = 0; p < 2; ++p) {
                int e = e0 + p * 8;
                float acc = bm2[o];
                #pragma unroll 8
                for (int i = 0; i < 32; ++i) acc += Wm2_s[o * 33 + i] * mr_s[e * 33 + i];
                msg_s[e * 33 + o] = acc;
            }
        }
        __syncthreads();
        {
            float* gi_g = ws + WS_GI;
            for (int idx = t; idx < 1536; idx += 256) {
                int e = idx / 96, o = idx - e * 96;
                float acc = bih[o];
                #pragma unroll 8
                for (int i = 0; i < 32; ++i) acc += Wih_s[o * 33 + i] * msg_s[e * 33 + i];
                gi_g[idx] = acc;  // [e][96]
            }
        }
        return;
    }

    // blocks 0..63: fold the memory -> out bulk copy (256 KB)
    if (bx < 64) {
        int g = bx * 256 + t;
        ((float4*)(out + 16))[g] = ((const float4*)mem)[g];
    }

    // ---- node path: 8 nodes per block ----
    const int j = t >> 5, o = t & 31;
    const int n = bx * 8 + j;

    for (int idx = t; idx < 1024; idx += 256) {  // Wemb 4096 floats
        float4 v = ((const float4*)Wemb)[idx];
        int r = idx >> 5, c = (idx & 31) * 4;
        We_s[r * 130 + c] = v.x; We_s[r * 130 + c + 1] = v.y;
        We_s[r * 130 + c + 2] = v.z; We_s[r * 130 + c + 3] = v.w;
    }
    for (int idx = t; idx < 768; idx += 256) {   // Wqkv 3072 floats
        float4 v = ((const float4*)Wqkv)[idx];
        int r = idx >> 3, c = (idx & 7) * 4;
        Wq_s[r * 33 + c] = v.x; Wq_s[r * 33 + c + 1] = v.y;
        Wq_s[r * 33 + c + 2] = v.z; Wq_s[r * 33 + c + 3] = v.w;
    }
    for (int idx = t; idx < 256; idx += 256) {   // nf tile 1024 floats
        float4 v = ((const float4*)nf)[(bx * 8 + (idx >> 5)) * 32 + (idx & 31)];
        int r = idx >> 5, c = (idx & 31) * 4;
        nf_s[r * 130 + c] = v.x; nf_s[r * 130 + c + 1] = v.y;
        nf_s[r * 130 + c + 2] = v.z; nf_s[r * 130 + c + 3] = v.w;
    }
    __syncthreads();

    float acc = bemb[o];
    {
        const float2* Wr = (const float2*)&We_s[o * 130];
        const float2* Nr = (const float2*)&nf_s[j * 130];
        float sx = 0.f, sy = 0.f;
        #pragma unroll 16
        for (int i = 0; i < 64; ++i) {
            float2 w = Wr[i], x = Nr[i];
            sx += w.x * x.x; sy += w.y * x.y;
        }
        acc += sx + sy;
    }
    x0_s[j * 33 + o] = acc;
    ws[WS_X0 + n * 32 + o] = acc;
    __syncthreads();

    #pragma unroll
    for (int c = 0; c < 3; ++c) {
        int oo = c * 32 + o;
        float a2 = bqkv[oo];
        #pragma unroll 8
        for (int i = 0; i < 32; ++i) a2 += Wq_s[oo * 33 + i] * x0_s[j * 33 + i];
        int h = o >> 3, d = o & 7;
        float* base = ws + (c == 0 ? WS_QT : (c == 1 ? WS_KT : WS_VT));
        base[h * 16384 + n * 8 + d] = a2;  // [h][n][d]
    }
}

// ---------------------------------------------------------------------------
// K2: attention for the 32 gathered query slots ONLY.
// grid 128 = slot(32) x kslice(4); block 256 = head(4) x 64 lanes.
// ---------------------------------------------------------------------------
__global__ __launch_bounds__(256) void k2_attn(
    const int* __restrict__ src, const int* __restrict__ dst,
    float* __restrict__ ws)
{
    const int t = threadIdx.x, bx = blockIdx.x;
    const int s  = bx >> 2;       // slot 0..31
    const int ks = bx & 3;        // key slice 0..3 (512 keys each)
    const int h  = t >> 6;        // head
    const int l  = t & 63;

    const int e = s >> 1;
    const int n = (s & 1) ? dst[e] : src[e];

    const float* qg = ws + WS_QT + h * 16384 + n * 8;
    const float4 qa  = *(const float4*)qg;
    const float4 qb4 = *(const float4*)(qg + 4);
    const float* kbase = ws + WS_KT + h * 16384;
    const float* vbase = ws + WS_VT + h * 16384;

    float4 oa = make_float4(0.f, 0.f, 0.f, 0.f);
    float4 ob = make_float4(0.f, 0.f, 0.f, 0.f);
    float ssum = 0.f;
    const float scale = 0.35355339059327373f;  // 1/sqrt(8)

    #pragma unroll
    for (int i = 0; i < 8; ++i) {
        const int key = ks * 512 + i * 64 + l;
        const float4 ka = *(const float4*)(kbase + key * 8);
        const float4 kb = *(const float4*)(kbase + key * 8 + 4);
        const float sc = (dot4_(qa, ka) + dot4_(qb4, kb)) * scale;
        const float p = __expf(sc);
        ssum += p;
        const float4 va = *(const float4*)(vbase + key * 8);
        const float4 vb = *(const float4*)(vbase + key * 8 + 4);
        oa.x += p * va.x; oa.y += p * va.y; oa.z += p * va.z; oa.w += p * va.w;
        ob.x += p * vb.x; ob.y += p * vb.y; ob.z += p * vb.z; ob.w += p * vb.w;
    }

    #pragma unroll
    for (int m = 1; m <= 32; m <<= 1) {
        ssum += __shfl_xor(ssum, m);
        oa.x += __shfl_xor(oa.x, m); oa.y += __shfl_xor(oa.y, m);
        oa.z += __shfl_xor(oa.z, m); oa.w += __shfl_xor(oa.w, m);
        ob.x += __shfl_xor(ob.x, m); ob.y += __shfl_xor(ob.y, m);
        ob.z += __shfl_xor(ob.z, m); ob.w += __shfl_xor(ob.w, m);
    }
    if (l == 0) {
        float* p = ws + WS_PART + ((s * 4 + h) * 4 + ks) * 12;
        *(float4*)p       = oa;
        *(float4*)(p + 4) = ob;
        p[8] = ssum;
    }
}

// ---------------------------------------------------------------------------
// K34: one block, 1024 threads. Phase 1 (all 32 slots in parallel): combine
// attn partials -> Wo -> LN1 -> FFN -> LN2 -> SCN LN relu (sout in LDS).
// Phase 2: edge-head MLP -> logits. Phase 3: wave-0 GRU scan over 16 edges.
// ---------------------------------------------------------------------------
__global__ __launch_bounds__(1024) void k34_post_scan(
    const int* __restrict__ src, const int* __restrict__ dst,
    const float* __restrict__ mem,
    const float* __restrict__ Wo, const float* __restrict__ bo,
    const float* __restrict__ g1, const float* __restrict__ be1,
    const float* __restrict__ Wf1, const float* __restrict__ bf1,
    const float* __restrict__ Wf2, const float* __restrict__ bf2,
    const float* __restrict__ g2, const float* __restrict__ be2,
    const float* __restrict__ Wscn, const float* __restrict__ bscn,
    const float* __restrict__ gscn, const float* __restrict__ bescn,
    const float* __restrict__ Whh, const float* __restrict__ bhh,
    const float* __restrict__ We1, const float* __restrict__ be1e,
    const float* __restrict__ We2, const float* __restrict__ be2e,
    const float* __restrict__ We3, const float* __restrict__ be3,
    float* __restrict__ ws, float* __restrict__ out)
{
    __shared__ float Wo_s[32 * 33];
    __shared__ float Wf1_s[64 * 33];
    __shared__ float Wf2_s[32 * 65];
    __shared__ float Ws_s[16 * 33];
    __shared__ float arow[32 * 33];   // attn-out; later reused as edge cat (16*33)
    __shared__ float x1s[32 * 33];
    __shared__ float fs[32 * 65];     // FFN hidden; later h1 @ [0,528), h2 @ [600,872)
    __shared__ float sout_s[32 * 17];
    __shared__ float We1_s[32 * 33];
    __shared__ float We2_s[16 * 33];
    __shared__ float gi_s[16 * 97];
    __shared__ __align__(16) float slots[32 * 36];
    __shared__ int nid_s[32], fid_s[32], last_s[32];

    const int t = threadIdx.x;
    const int j = t >> 5, o = t & 31;   // slot j = 0..31

    // Whh rows into wave-0 registers (independent global loads, issued early)
    float4 w1[8], w2[8], w3[8];
    float b1 = 0.f, b2 = 0.f, b3 = 0.f;
    if (t < 64) {
        const int r2 = (t < 32) ? t + 64 : t - 32;
        const int r3 = t + 32;
        #pragma unroll
        for (int c = 0; c < 8; ++c) {
            w1[c] = ((const float4*)Whh)[t * 8 + c];
            w2[c] = ((const float4*)Whh)[r2 * 8 + c];
            w3[c] = ((const float4*)Whh)[r3 * 8 + c];
        }
        b1 = bhh[t]; b2 = bhh[r2]; b3 = bhh[r3];
    }

    // ---- A0: stage everything independent ----
    for (int idx = t; idx < 1024; idx += 1024) { int r = idx >> 5, c = idx & 31; Wo_s[r * 33 + c] = Wo[idx]; }
    for (int idx = t; idx < 2048; idx += 1024) { int r = idx >> 5, c = idx & 31; Wf1_s[r * 33 + c] = Wf1[idx]; }
    for (int idx = t; idx < 2048; idx += 1024) { int r = idx >> 6, c = idx & 63; Wf2_s[r * 65 + c] = Wf2[idx]; }
    for (int idx = t; idx < 512;  idx += 1024) { int r = idx >> 5, c = idx & 31; Ws_s[r * 33 + c] = Wscn[idx]; }
    for (int idx = t; idx < 1024; idx += 1024) { int r = idx >> 5, c = idx & 31; We1_s[r * 33 + c] = We1[idx]; }
    for (int idx = t; idx < 512;  idx += 1024) { int r = idx >> 5, c = idx & 31; We2_s[r * 33 + c] = We2[idx]; }
    for (int idx = t; idx < 1536; idx += 1024) { int e = idx / 96, oo = idx - e * 96; gi_s[e * 97 + oo] = ws[WS_GI + idx]; }
    if (t < 32) nid_s[t] = (t & 1) ? dst[t >> 1] : src[t >> 1];

    const int ej = j >> 1;
    const int n = (j & 1) ? dst[ej] : src[ej];
    { // combine 4 key-slice partials for this slot
        const int h = o >> 3, d = o & 7;
        float num = 0.f, den = 0.f;
        #pragma unroll
        for (int ks = 0; ks < 4; ++ks) {
            const float* p = ws + WS_PART + ((j * 4 + h) * 4 + ks) * 12;
            num += p[d];
            den += p[8];
        }
        arow[j * 33 + o] = num / den;
    }
    const float x0v = ws[WS_X0 + n * 32 + o];
    __syncthreads();

    // ---- A1: fid/last; Wo GEMM + residual + LN1 -> x1s ----
    if (t < 32) {
        int me = nid_s[t], f = t;
        for (int j2 = 0; j2 < t; ++j2) if (nid_s[j2] == me) { f = j2; break; }
        fid_s[t] = f;
        int isl = 1;
        for (int j2 = t + 1; j2 < 32; ++j2) if (nid_s[j2] == me) { isl = 0; break; }
        last_s[t] = isl;
    }
    float a = bo[o];
    #pragma unroll 8
    for (int i = 0; i < 32; ++i) a += Wo_s[o * 33 + i] * arow[j * 33 + i];
    float t1 = x0v + a;
    float mu = t1;
    #pragma unroll
    for (int m = 16; m >= 1; m >>= 1) mu += __shfl_xor(mu, m, 32);
    mu *= (1.f / 32.f);
    float dv = t1 - mu;
    float var = dv * dv;
    #pragma unroll
    for (int m = 16; m >= 1; m >>= 1) var += __shfl_xor(var, m, 32);
    var *= (1.f / 32.f);
    float x1 = dv * rsqrtf(var + 1e-5f) * g1[o] + be1[o];
    x1s[j * 33 + o] = x1;
    __syncthreads();

    // ---- A2: slot memory load; FFN1 + gelu -> fs ----
    if (t < 1024) {
        int j2 = t >> 5;
        if (fid_s[j2] == j2) slots[j2 * 36 + o] = mem[nid_s[j2] * 32 + o];
    }
    #pragma unroll
    for (int c = 0; c < 2; ++c) {
        int oo = c * 32 + o;
        float f = bf1[oo];
        #pragma unroll 8
        for (int i = 0; i < 32; ++i) f += Wf1_s[oo * 33 + i] * x1s[j * 33 + i];
        fs[j * 65 + oo] = 0.5f * f * (1.f + erff(f * 0.70710678118654752f));
    }
    __syncthreads();

    // ---- A3: FFN2 + residual + LN2 -> x1s (x2) ----
    float f2 = bf2[o];
    #pragma unroll 8
    for (int i = 0; i < 64; ++i) f2 += Wf2_s[o * 65 + i] * fs[j * 65 + i];
    float t2 = x1 + f2;
    float mu2 = t2;
    #pragma unroll
    for (int m = 16; m >= 1; m >>= 1) mu2 += __shfl_xor(mu2, m, 32);
    mu2 *= (1.f / 32.f);
    float dv2 = t2 - mu2;
    float var2 = dv2 * dv2;
    #pragma unroll
    for (int m = 16; m >= 1; m >>= 1) var2 += __shfl_xor(var2, m, 32);
    var2 *= (1.f / 32.f);
    float x2 = dv2 * rsqrtf(var2 + 1e-5f) * g2[o] + be2[o];
    __syncthreads();
    x1s[j * 33 + o] = x2;
    __syncthreads();

    // ---- A4: SCN + LN(16) + relu -> sout_s ----
    if (o < 16) {
        float sc = bscn[o];
        #pragma unroll 8
        for (int i = 0; i < 32; ++i) sc += Ws_s[o * 33 + i] * x1s[j * 33 + i];
        float m16 = sc;
        #pragma unroll
        for (int m = 8; m >= 1; m >>= 1) m16 += __shfl_xor(m16, m, 16);
        m16 *= (1.f / 16.f);
        float d16 = sc - m16;
        float v16 = d16 * d16;
        #pragma unroll
        for (int m = 8; m >= 1; m >>= 1) v16 += __shfl_xor(v16, m, 16);
        v16 *= (1.f / 16.f);
        float sv = d16 * rsqrtf(v16 + 1e-5f) * gscn[o] + bescn[o];
        sout_s[j * 17 + o] = fmaxf(sv, 0.f);
    }
    __syncthreads();

    // ---- A5: build edge cat into arow ----
    if (t < 512) {
        int e = t >> 5, i = t & 31;
        arow[e * 33 + i] = (i < 16) ? sout_s[(2 * e) * 17 + i]
                                    : sout_s[(2 * e + 1) * 17 + (i - 16)];
    }
    __syncthreads();

    // ---- A6: h1 = relu(cat @ We1^T) ----
    if (t < 512) {
        int e = t >> 5;
        float acc = be1e[o];
        #pragma unroll 8
        for (int i = 0; i < 32; ++i) acc += We1_s[o * 33 + i] * arow[e * 33 + i];
        fs[e * 33 + o] = fmaxf(acc, 0.f);
    }
    __syncthreads();

    // ---- A7: h2 = relu(h1 @ We2^T) ----
    if (t < 256) {
        int e = t >> 4, o2 = t & 15;
        float acc = be2e[o2];
        #pragma unroll 8
        for (int i = 0; i < 32; ++i) acc += We2_s[o2 * 33 + i] * fs[e * 33 + i];
        fs[600 + e * 17 + o2] = fmaxf(acc, 0.f);
    }
    __syncthreads();

    // ---- A8: logits ----
    if (t < 16) {
        float acc = be3[0];
        #pragma unroll
        for (int i = 0; i < 16; ++i) acc += We3[i] * fs[600 + t * 17 + i];
        out[t] = acc;
    }
    __syncthreads();

    // ---- GRU scan: wave 0 only (lockstep; fence for LDS ordering) ----
    if (t < 64) {
        const bool lowhalf = (t < 32);
        for (int e = 0; e < 16; ++e) {
            const int js = 2 * e, jd = 2 * e + 1;
            const int ss = fid_s[js], sd = fid_s[jd];
            const bool same = (nid_s[js] == nid_s[jd]);
            const int npass = same ? 2 : 1;
            for (int pass = 0; pass < npass; ++pass) {
                const bool do_src = (!same) || (pass == 0);
                const bool do_dst = (!same) || (pass == 1);
                float acc1 = b1, acc2 = b2, acc3 = b3;
                #pragma unroll
                for (int c = 0; c < 8; ++c) {
                    const float4 hs4 = *(const float4*)&slots[ss * 36 + 4 * c];
                    const float4 hd4 = *(const float4*)&slots[sd * 36 + 4 * c];
                    acc1 += dot4_(w1[c], hs4);
                    const float4 hm = lowhalf ? hs4 : hd4;
                    acc2 += dot4_(w2[c], hm);
                    acc3 += dot4_(w3[c], hd4);
                }
                const float shv = __shfl_xor(lowhalf ? acc3 : acc1, 32);
                const float hr = lowhalf ? acc1 : acc2;
                const float hz = shv;
                const float hn = lowhalf ? acc2 : acc3;
                const float ir  = gi_s[e * 97 + o];
                const float iz  = gi_s[e * 97 + 32 + o];
                const float inn = gi_s[e * 97 + 64 + o];
                const float r = sigmoidf_(ir + hr);
                const float z = sigmoidf_(iz + hz);
                const float nn = tanhf_(inn + r * hn);
                const int slot = lowhalf ? ss : sd;
                const float hold = slots[slot * 36 + o];
                const float hnew = (1.f - z) * nn + z * hold;
                const bool wr = lowhalf ? do_src : do_dst;
                if (wr) slots[slot * 36 + o] = hnew;
                __threadfence_block();
            }
        }
    }
    __syncthreads();

    // ---- writeback last occurrence of each node ----
    {
        int j2 = t >> 5;
        if (t < 1024 && last_s[j2]) out[16 + nid_s[j2] * 32 + o] = slots[fid_s[j2] * 36 + o];
    }
}

// ---------------------------------------------------------------------------
extern "C" void kernel_launch(void* const* d_in, const int* in_sizes, int n_in,
                              void* d_out, int out_size, void* d_ws, size_t ws_size,
                              hipStream_t stream)
{
    (void)in_sizes; (void)n_in; (void)out_size; (void)ws_size;
    const int*   src   = (const int*)d_in[0];
    const int*   dst   = (const int*)d_in[1];
    const float* ef    = (const float*)d_in[2];
    const float* nf    = (const float*)d_in[4];
    const float* mem   = (const float*)d_in[6];
    const float* Wemb  = (const float*)d_in[7];
    const float* bemb  = (const float*)d_in[8];
    const float* Wqkv  = (const float*)d_in[9];
    const float* bqkv  = (const float*)d_in[10];
    const float* Wo    = (const float*)d_in[11];
    const float* bo    = (const float*)d_in[12];
    const float* g1    = (const float*)d_in[13];
    const float* be1   = (const float*)d_in[14];
    const float* g2    = (const float*)d_in[15];
    const float* be2   = (const float*)d_in[16];
    const float* Wf1   = (const float*)d_in[17];
    const float* bf1   = (const float*)d_in[18];
    const float* Wf2   = (const float*)d_in[19];
    const float* bf2   = (const float*)d_in[20];
    const float* Wscn  = (const float*)d_in[21];
    const float* bscn  = (const float*)d_in[22];
    const float* gscn  = (const float*)d_in[23];
    const float* bescn = (const float*)d_in[24];
    const float* We1   = (const float*)d_in[25];
    const float* be1e  = (const float*)d_in[26];
    const float* We2   = (const float*)d_in[27];
    const float* be2e  = (const float*)d_in[28];
    const float* We3   = (const float*)d_in[29];
    const float* be3   = (const float*)d_in[30];
    const float* Wih   = (const float*)d_in[31];
    const float* bih   = (const float*)d_in[32];
    const float* Whh   = (const float*)d_in[33];
    const float* bhh   = (const float*)d_in[34];
    const float* Wm1   = (const float*)d_in[35];
    const float* bm1   = (const float*)d_in[36];
    const float* Wm2   = (const float*)d_in[37];
    const float* bm2   = (const float*)d_in[38];
    float* out = (float*)d_out;
    float* ws  = (float*)d_ws;

    hipLaunchKernelGGL(k1_embed_qkv, dim3(257), dim3(256), 0, stream,
        nf, Wemb, bemb, Wqkv, bqkv, mem, src, dst, ef, Wm1, bm1, Wm2, bm2, Wih, bih, ws, out);
    hipLaunchKernelGGL(k2_attn, dim3(128), dim3(256), 0, stream, src, dst, ws);
    hipLaunchKernelGGL(k34_post_scan, dim3(1), dim3(1024), 0, stream,
        src, dst, mem, Wo, bo, g1, be1, Wf1, bf1, Wf2, bf2, g2, be2,
        Wscn, bscn, gscn, bescn, Whh, bhh, We1, be1e, We2, be2e, We3, be3, ws, out);
}

// Round 4
// 179.469 us; speedup vs baseline: 1.1321x; 1.1321x over previous
//
#include <hip/hip_runtime.h>
#include <math.h>

#define NN   2048
#define BB   16

// ws layout (float offsets)
#define WS_X0   0
#define WS_QT   65536
#define WS_KT   131072
#define WS_VT   196608
#define WS_PART 262144   // [32 slot][4 h][4 kslice][12]: o[8], ssum, pad
#define WS_GI   268800   // [16 edge][96]

__device__ __forceinline__ float sigmoidf_(float x) { return 1.0f / (1.0f + __expf(-x)); }
__device__ __forceinline__ float tanhf_(float x) {
    float ex = __expf(2.0f * x);
    return 1.0f - 2.0f / (ex + 1.0f);
}
__device__ __forceinline__ float dot4_(float4 a, float4 b) {
    return a.x*b.x + a.y*b.y + a.z*b.z + a.w*b.w;
}

// ---------------------------------------------------------------------------
// K1: blocks 0..255: x0 = nf@Wemb^T+b ; qkv = x0@Wqkv^T+b  (head-major q/k/v)
//     blocks 0..63 additionally copy memory -> out[16..]
//     block 256:     messages -> gi = msg@Wih^T + bih   (for the GRU scan)
// Staging is BATCHED: all global loads into regs first (1 latency round),
// then LDS writes — avoids per-iteration load->ds_write serialization.
// ---------------------------------------------------------------------------
__global__ __launch_bounds__(256) void k1_embed_qkv(
    const float* __restrict__ nf, const float* __restrict__ Wemb, const float* __restrict__ bemb,
    const float* __restrict__ Wqkv, const float* __restrict__ bqkv,
    const float* __restrict__ mem, const int* __restrict__ src, const int* __restrict__ dst,
    const float* __restrict__ ef,
    const float* __restrict__ Wm1, const float* __restrict__ bm1,
    const float* __restrict__ Wm2, const float* __restrict__ bm2,
    const float* __restrict__ Wih, const float* __restrict__ bih,
    float* __restrict__ ws, float* __restrict__ out)
{
    // node path LDS (stride 130: float2 rows, 2-way bank aliasing = free)
    __shared__ float We_s[32 * 130];
    __shared__ float nf_s[8 * 130];
    __shared__ float x0_s[8 * 33];
    __shared__ float Wq_s[96 * 33];
    // message path LDS
    __shared__ __align__(16) float Wm1_s[32 * 67];
    __shared__ float Wm2_s[32 * 33];
    __shared__ float Wih_s[96 * 33];
    __shared__ float min_s[16 * 67];
    __shared__ float mr_s[16 * 33];
    __shared__ float msg_s[16 * 33];

    const int t = threadIdx.x, bx = blockIdx.x;

    if (bx == 256) {
        // ---- message path: batched staging ----
        float4 rm1[3], rm2, rih[3];
        float rmin[5];
        #pragma unroll
        for (int k = 0; k < 3; ++k) {
            int idx = t + 256 * k;
            rm1[k] = (idx < 536) ? ((const float4*)Wm1)[idx] : make_float4(0,0,0,0);
        }
        rm2 = ((const float4*)Wm2)[t];
        #pragma unroll
        for (int k = 0; k < 3; ++k) rih[k] = ((const float4*)Wih)[t + 256 * k];
        #pragma unroll
        for (int k = 0; k < 5; ++k) {
            int idx = t + 256 * k;
            rmin[k] = 0.f;
            if (idx < 1072) {
                int e = idx / 67, i = idx - e * 67;
                if (i < 32)      rmin[k] = mem[src[e] * 32 + i];
                else if (i < 64) rmin[k] = mem[dst[e] * 32 + (i - 32)];
                else             rmin[k] = ef[e * 3 + (i - 64)];
            }
        }
        #pragma unroll
        for (int k = 0; k < 3; ++k) {
            int idx = t + 256 * k;
            if (idx < 536) ((float4*)Wm1_s)[idx] = rm1[k];
        }
        { int o = t >> 3, i = (t & 7) * 4;
          Wm2_s[o * 33 + i] = rm2.x; Wm2_s[o * 33 + i + 1] = rm2.y;
          Wm2_s[o * 33 + i + 2] = rm2.z; Wm2_s[o * 33 + i + 3] = rm2.w; }
        #pragma unroll
        for (int k = 0; k < 3; ++k) {
            int idx = t + 256 * k;
            int o = idx >> 3, i = (idx & 7) * 4;
            Wih_s[o * 33 + i] = rih[k].x; Wih_s[o * 33 + i + 1] = rih[k].y;
            Wih_s[o * 33 + i + 2] = rih[k].z; Wih_s[o * 33 + i + 3] = rih[k].w;
        }
        #pragma unroll
        for (int k = 0; k < 5; ++k) {
            int idx = t + 256 * k;
            if (idx < 1072) min_s[idx] = rmin[k];
        }
        __syncthreads();
        {
            int o = t & 31, e0 = t >> 5;
            for (int p = 0; p < 2; ++p) {
                int e = e0 + p * 8;
                float acc = bm1[o];
                for (int i = 0; i < 67; ++i) acc += Wm1_s[o * 67 + i] * min_s[e * 67 + i];
                mr_s[e * 33 + o] = fmaxf(acc, 0.f);
            }
        }
        __syncthreads();
        {
            int o = t & 31, e0 = t >> 5;
            for (int p = 0; p < 2; ++p) {
                int e = e0 + p * 8;
                float acc = bm2[o];
                #pragma unroll 8
                for (int i = 0; i < 32; ++i) acc += Wm2_s[o * 33 + i] * mr_s[e * 33 + i];
                msg_s[e * 33 + o] = acc;
            }
        }
        __syncthreads();
        {
            float* gi_g = ws + WS_GI;
            for (int idx = t; idx < 1536; idx += 256) {
                int e = idx / 96, o = idx - e * 96;
                float acc = bih[o];
                #pragma unroll 8
                for (int i = 0; i < 32; ++i) acc += Wih_s[o * 33 + i] * msg_s[e * 33 + i];
                gi_g[idx] = acc;  // [e][96]
            }
        }
        return;
    }

    // ---- node path: batched staging ----
    float4 rA[4], rB[3], rC;
    #pragma unroll
    for (int k = 0; k < 4; ++k) rA[k] = ((const float4*)Wemb)[t + 256 * k];
    #pragma unroll
    for (int k = 0; k < 3; ++k) rB[k] = ((const float4*)Wqkv)[t + 256 * k];
    rC = ((const float4*)nf)[bx * 256 + t];

    // blocks 0..63: fold the memory -> out bulk copy (256 KB)
    if (bx < 64) {
        int g = bx * 256 + t;
        ((float4*)(out + 16))[g] = ((const float4*)mem)[g];
    }

    #pragma unroll
    for (int k = 0; k < 4; ++k) {
        int idx = t + 256 * k;
        int r = idx >> 5, c = (idx & 31) * 4;
        We_s[r * 130 + c] = rA[k].x; We_s[r * 130 + c + 1] = rA[k].y;
        We_s[r * 130 + c + 2] = rA[k].z; We_s[r * 130 + c + 3] = rA[k].w;
    }
    #pragma unroll
    for (int k = 0; k < 3; ++k) {
        int idx = t + 256 * k;
        int r = idx >> 3, c = (idx & 7) * 4;
        Wq_s[r * 33 + c] = rB[k].x; Wq_s[r * 33 + c + 1] = rB[k].y;
        Wq_s[r * 33 + c + 2] = rB[k].z; Wq_s[r * 33 + c + 3] = rB[k].w;
    }
    {
        int r = t >> 5, c = (t & 31) * 4;
        nf_s[r * 130 + c] = rC.x; nf_s[r * 130 + c + 1] = rC.y;
        nf_s[r * 130 + c + 2] = rC.z; nf_s[r * 130 + c + 3] = rC.w;
    }
    __syncthreads();

    const int j = t >> 5, o = t & 31;
    const int n = bx * 8 + j;

    float acc = bemb[o];
    {
        const float2* Wr = (const float2*)&We_s[o * 130];
        const float2* Nr = (const float2*)&nf_s[j * 130];
        float sx = 0.f, sy = 0.f;
        #pragma unroll 16
        for (int i = 0; i < 64; ++i) {
            float2 w = Wr[i], x = Nr[i];
            sx += w.x * x.x; sy += w.y * x.y;
        }
        acc += sx + sy;
    }
    x0_s[j * 33 + o] = acc;
    ws[WS_X0 + n * 32 + o] = acc;
    __syncthreads();

    #pragma unroll
    for (int c = 0; c < 3; ++c) {
        int oo = c * 32 + o;
        float a2 = bqkv[oo];
        #pragma unroll 8
        for (int i = 0; i < 32; ++i) a2 += Wq_s[oo * 33 + i] * x0_s[j * 33 + i];
        int h = o >> 3, d = o & 7;
        float* base = ws + (c == 0 ? WS_QT : (c == 1 ? WS_KT : WS_VT));
        base[h * 16384 + n * 8 + d] = a2;  // [h][n][d]
    }
}

// ---------------------------------------------------------------------------
// K2: attention for the 32 gathered query slots ONLY.
// grid 128 = slot(32) x kslice(4); block 256 = head(4) x 64 lanes.
// ---------------------------------------------------------------------------
__global__ __launch_bounds__(256) void k2_attn(
    const int* __restrict__ src, const int* __restrict__ dst,
    float* __restrict__ ws)
{
    const int t = threadIdx.x, bx = blockIdx.x;
    const int s  = bx >> 2;       // slot 0..31
    const int ks = bx & 3;        // key slice 0..3 (512 keys each)
    const int h  = t >> 6;        // head
    const int l  = t & 63;

    const int e = s >> 1;
    const int n = (s & 1) ? dst[e] : src[e];

    const float* qg = ws + WS_QT + h * 16384 + n * 8;
    const float4 qa  = *(const float4*)qg;
    const float4 qb4 = *(const float4*)(qg + 4);
    const float* kbase = ws + WS_KT + h * 16384;
    const float* vbase = ws + WS_VT + h * 16384;

    float4 oa = make_float4(0.f, 0.f, 0.f, 0.f);
    float4 ob = make_float4(0.f, 0.f, 0.f, 0.f);
    float ssum = 0.f;
    const float scale = 0.35355339059327373f;  // 1/sqrt(8)

    #pragma unroll
    for (int i = 0; i < 8; ++i) {
        const int key = ks * 512 + i * 64 + l;
        const float4 ka = *(const float4*)(kbase + key * 8);
        const float4 kb = *(const float4*)(kbase + key * 8 + 4);
        const float sc = (dot4_(qa, ka) + dot4_(qb4, kb)) * scale;
        const float p = __expf(sc);
        ssum += p;
        const float4 va = *(const float4*)(vbase + key * 8);
        const float4 vb = *(const float4*)(vbase + key * 8 + 4);
        oa.x += p * va.x; oa.y += p * va.y; oa.z += p * va.z; oa.w += p * va.w;
        ob.x += p * vb.x; ob.y += p * vb.y; ob.z += p * vb.z; ob.w += p * vb.w;
    }

    #pragma unroll
    for (int m = 1; m <= 32; m <<= 1) {
        ssum += __shfl_xor(ssum, m);
        oa.x += __shfl_xor(oa.x, m); oa.y += __shfl_xor(oa.y, m);
        oa.z += __shfl_xor(oa.z, m); oa.w += __shfl_xor(oa.w, m);
        ob.x += __shfl_xor(ob.x, m); ob.y += __shfl_xor(ob.y, m);
        ob.z += __shfl_xor(ob.z, m); ob.w += __shfl_xor(ob.w, m);
    }
    if (l == 0) {
        float* p = ws + WS_PART + ((s * 4 + h) * 4 + ks) * 12;
        *(float4*)p       = oa;
        *(float4*)(p + 4) = ob;
        p[8] = ssum;
    }
}

// ---------------------------------------------------------------------------
// K34: one block, 256 threads, __launch_bounds__(256,1) -> no VGPR cap/spill.
// Slot phases iterate 4x (8 slots per pass). GRU scan on wave 0 with Whh in
// registers. All staging batched (regs first, then LDS).
// ---------------------------------------------------------------------------
__global__ __launch_bounds__(256, 1) void k34_post_scan(
    const int* __restrict__ src, const int* __restrict__ dst,
    const float* __restrict__ mem,
    const float* __restrict__ Wo, const float* __restrict__ bo,
    const float* __restrict__ g1, const float* __restrict__ be1,
    const float* __restrict__ Wf1, const float* __restrict__ bf1,
    const float* __restrict__ Wf2, const float* __restrict__ bf2,
    const float* __restrict__ g2, const float* __restrict__ be2,
    const float* __restrict__ Wscn, const float* __restrict__ bscn,
    const float* __restrict__ gscn, const float* __restrict__ bescn,
    const float* __restrict__ Whh, const float* __restrict__ bhh,
    const float* __restrict__ We1, const float* __restrict__ be1e,
    const float* __restrict__ We2, const float* __restrict__ be2e,
    const float* __restrict__ We3, const float* __restrict__ be3,
    float* __restrict__ ws, float* __restrict__ out)
{
    __shared__ float Wo_s[32 * 33];
    __shared__ float Wf1_s[64 * 33];
    __shared__ float Wf2_s[32 * 65];
    __shared__ float Ws_s[16 * 33];
    __shared__ float arow[32 * 33];   // attn-out; later reused as edge cat (16*33)
    __shared__ float x1s[32 * 33];
    __shared__ float fs[32 * 65];     // FFN hidden; later h1 @ [0,528), h2 @ [600,872)
    __shared__ float sout_s[32 * 17];
    __shared__ float We1_s[32 * 33];
    __shared__ float We2_s[16 * 33];
    __shared__ float gi_s[16 * 97];
    __shared__ __align__(16) float slots[32 * 36];
    __shared__ int nid_s[32], fid_s[32], last_s[32];

    const int t = threadIdx.x;
    const int j0 = t >> 5, o = t & 31;

    // Whh rows into wave-0 registers (issued first; latency hides under staging)
    float4 w1[8], w2[8], w3[8];
    float b1 = 0.f, b2 = 0.f, b3 = 0.f;
    if (t < 64) {
        const int r2 = (t < 32) ? t + 64 : t - 32;
        const int r3 = t + 32;
        #pragma unroll
        for (int c = 0; c < 8; ++c) {
            w1[c] = ((const float4*)Whh)[t * 8 + c];
            w2[c] = ((const float4*)Whh)[r2 * 8 + c];
            w3[c] = ((const float4*)Whh)[r3 * 8 + c];
        }
        b1 = bhh[t]; b2 = bhh[r2]; b3 = bhh[r3];
    }

    // ---- batched staging: all loads into regs, then LDS writes ----
    float4 rWo, rF1a, rF1b, rF2a, rF2b, rE1, rWs, rE2, rG0, rG1;
    rWo  = ((const float4*)Wo)[t];
    rF1a = ((const float4*)Wf1)[t]; rF1b = ((const float4*)Wf1)[t + 256];
    rF2a = ((const float4*)Wf2)[t]; rF2b = ((const float4*)Wf2)[t + 256];
    rE1  = ((const float4*)We1)[t];
    rG0  = ((const float4*)(ws + WS_GI))[t];
    if (t < 128) {
        rWs = ((const float4*)Wscn)[t];
        rE2 = ((const float4*)We2)[t];
        rG1 = ((const float4*)(ws + WS_GI))[t + 256];
    }
    if (t < 32) nid_s[t] = (t & 1) ? dst[t >> 1] : src[t >> 1];

    { int r = t >> 3, c = (t & 7) * 4;
      Wo_s[r * 33 + c] = rWo.x; Wo_s[r * 33 + c + 1] = rWo.y;
      Wo_s[r * 33 + c + 2] = rWo.z; Wo_s[r * 33 + c + 3] = rWo.w;
      We1_s[r * 33 + c] = rE1.x; We1_s[r * 33 + c + 1] = rE1.y;
      We1_s[r * 33 + c + 2] = rE1.z; We1_s[r * 33 + c + 3] = rE1.w; }
    { int r = t >> 3, c = (t & 7) * 4;
      Wf1_s[r * 33 + c] = rF1a.x; Wf1_s[r * 33 + c + 1] = rF1a.y;
      Wf1_s[r * 33 + c + 2] = rF1a.z; Wf1_s[r * 33 + c + 3] = rF1a.w;
      int r2 = (t + 256) >> 3, c2 = ((t + 256) & 7) * 4;
      Wf1_s[r2 * 33 + c2] = rF1b.x; Wf1_s[r2 * 33 + c2 + 1] = rF1b.y;
      Wf1_s[r2 * 33 + c2 + 2] = rF1b.z; Wf1_s[r2 * 33 + c2 + 3] = rF1b.w; }
    { int r = t >> 4, c = (t & 15) * 4;
      Wf2_s[r * 65 + c] = rF2a.x; Wf2_s[r * 65 + c + 1] = rF2a.y;
      Wf2_s[r * 65 + c + 2] = rF2a.z; Wf2_s[r * 65 + c + 3] = rF2a.w;
      int r2 = (t + 256) >> 4, c2 = ((t + 256) & 15) * 4;
      Wf2_s[r2 * 65 + c2] = rF2b.x; Wf2_s[r2 * 65 + c2 + 1] = rF2b.y;
      Wf2_s[r2 * 65 + c2 + 2] = rF2b.z; Wf2_s[r2 * 65 + c2 + 3] = rF2b.w; }
    { int f = 4 * t, e = f / 96, off = f - e * 96;
      gi_s[e * 97 + off] = rG0.x; gi_s[e * 97 + off + 1] = rG0.y;
      gi_s[e * 97 + off + 2] = rG0.z; gi_s[e * 97 + off + 3] = rG0.w; }
    if (t < 128) {
        int r = t >> 3, c = (t & 7) * 4;
        Ws_s[r * 33 + c] = rWs.x; Ws_s[r * 33 + c + 1] = rWs.y;
        Ws_s[r * 33 + c + 2] = rWs.z; Ws_s[r * 33 + c + 3] = rWs.w;
        We2_s[r * 33 + c] = rE2.x; We2_s[r * 33 + c + 1] = rE2.y;
        We2_s[r * 33 + c + 2] = rE2.z; We2_s[r * 33 + c + 3] = rE2.w;
        int f = 4 * (t + 256), e2 = f / 96, off = f - e2 * 96;
        gi_s[e2 * 97 + off] = rG1.x; gi_s[e2 * 97 + off + 1] = rG1.y;
        gi_s[e2 * 97 + off + 2] = rG1.z; gi_s[e2 * 97 + off + 3] = rG1.w;
    }

    // attn-partial combine + x0 gather for all 4 slot groups (pre-barrier: arow)
    float x0v[4];
    #pragma unroll
    for (int si = 0; si < 4; ++si) {
        const int jj = si * 8 + j0;
        const int ej = jj >> 1;
        const int n = (jj & 1) ? dst[ej] : src[ej];
        const int h = o >> 3, d = o & 7;
        float num = 0.f, den = 0.f;
        #pragma unroll
        for (int ks = 0; ks < 4; ++ks) {
            const float* p = ws + WS_PART + ((jj * 4 + h) * 4 + ks) * 12;
            num += p[d];
            den += p[8];
        }
        arow[jj * 33 + o] = num / den;
        x0v[si] = ws[WS_X0 + n * 32 + o];
    }
    __syncthreads();

    // fid/last
    if (t < 32) {
        int me = nid_s[t], f = t;
        for (int j2 = 0; j2 < t; ++j2) if (nid_s[j2] == me) { f = j2; break; }
        fid_s[t] = f;
        int isl = 1;
        for (int j2 = t + 1; j2 < 32; ++j2) if (nid_s[j2] == me) { isl = 0; break; }
        last_s[t] = isl;
    }
    __syncthreads();

    // slot memory gather (off the critical path; completes before GRU)
    #pragma unroll
    for (int k = 0; k < 4; ++k) {
        int j2 = j0 + 8 * k;
        if (fid_s[j2] == j2) slots[j2 * 36 + o] = mem[nid_s[j2] * 32 + o];
    }

    // ---- A1: Wo GEMM + residual + LN1 -> x1s ----
    #pragma unroll
    for (int si = 0; si < 4; ++si) {
        const int jj = si * 8 + j0;
        float a = bo[o];
        #pragma unroll 8
        for (int i = 0; i < 32; ++i) a += Wo_s[o * 33 + i] * arow[jj * 33 + i];
        float t1 = x0v[si] + a;
        float mu = t1;
        #pragma unroll
        for (int m = 16; m >= 1; m >>= 1) mu += __shfl_xor(mu, m, 32);
        mu *= (1.f / 32.f);
        float dv = t1 - mu;
        float var = dv * dv;
        #pragma unroll
        for (int m = 16; m >= 1; m >>= 1) var += __shfl_xor(var, m, 32);
        var *= (1.f / 32.f);
        x1s[jj * 33 + o] = dv * rsqrtf(var + 1e-5f) * g1[o] + be1[o];
    }
    __syncthreads();

    // ---- A2: FFN1 + gelu -> fs ----
    #pragma unroll
    for (int si = 0; si < 4; ++si) {
        const int jj = si * 8 + j0;
        #pragma unroll
        for (int c = 0; c < 2; ++c) {
            int oo = c * 32 + o;
            float f = bf1[oo];
            #pragma unroll 8
            for (int i = 0; i < 32; ++i) f += Wf1_s[oo * 33 + i] * x1s[jj * 33 + i];
            fs[jj * 65 + oo] = 0.5f * f * (1.f + erff(f * 0.70710678118654752f));
        }
    }
    __syncthreads();

    // ---- A3: FFN2 + residual + LN2 -> x1s (x2) ----
    #pragma unroll
    for (int si = 0; si < 4; ++si) {
        const int jj = si * 8 + j0;
        float f2 = bf2[o];
        #pragma unroll 8
        for (int i = 0; i < 64; ++i) f2 += Wf2_s[o * 65 + i] * fs[jj * 65 + i];
        float t2 = x1s[jj * 33 + o] + f2;
        float mu2 = t2;
        #pragma unroll
        for (int m = 16; m >= 1; m >>= 1) mu2 += __shfl_xor(mu2, m, 32);
        mu2 *= (1.f / 32.f);
        float dv2 = t2 - mu2;
        float var2 = dv2 * dv2;
        #pragma unroll
        for (int m = 16; m >= 1; m >>= 1) var2 += __shfl_xor(var2, m, 32);
        var2 *= (1.f / 32.f);
        x1s[jj * 33 + o] = dv2 * rsqrtf(var2 + 1e-5f) * g2[o] + be2[o];
    }
    __syncthreads();

    // ---- A4: SCN + LN(16) + relu -> sout_s ----
    if (o < 16) {
        #pragma unroll
        for (int si = 0; si < 4; ++si) {
            const int jj = si * 8 + j0;
            float sc = bscn[o];
            #pragma unroll 8
            for (int i = 0; i < 32; ++i) sc += Ws_s[o * 33 + i] * x1s[jj * 33 + i];
            float m16 = sc;
            #pragma unroll
            for (int m = 8; m >= 1; m >>= 1) m16 += __shfl_xor(m16, m, 16);
            m16 *= (1.f / 16.f);
            float d16 = sc - m16;
            float v16 = d16 * d16;
            #pragma unroll
            for (int m = 8; m >= 1; m >>= 1) v16 += __shfl_xor(v16, m, 16);
            v16 *= (1.f / 16.f);
            float sv = d16 * rsqrtf(v16 + 1e-5f) * gscn[o] + bescn[o];
            sout_s[jj * 17 + o] = fmaxf(sv, 0.f);
        }
    }
    __syncthreads();

    // ---- A5: build edge cat into arow ----
    #pragma unroll
    for (int k = 0; k < 2; ++k) {
        int idx = t + 256 * k;
        int e = idx >> 5, i = idx & 31;
        arow[e * 33 + i] = (i < 16) ? sout_s[(2 * e) * 17 + i]
                                    : sout_s[(2 * e + 1) * 17 + (i - 16)];
    }
    __syncthreads();

    // ---- A6: h1 = relu(cat @ We1^T) ----
    #pragma unroll
    for (int k = 0; k < 2; ++k) {
        int e = j0 + 8 * k;
        float acc = be1e[o];
        #pragma unroll 8
        for (int i = 0; i < 32; ++i) acc += We1_s[o * 33 + i] * arow[e * 33 + i];
        fs[e * 33 + o] = fmaxf(acc, 0.f);
    }
    __syncthreads();

    // ---- A7: h2 = relu(h1 @ We2^T) ----
    {
        int e = t >> 4, o2 = t & 15;
        float acc = be2e[o2];
        #pragma unroll 8
        for (int i = 0; i < 32; ++i) acc += We2_s[o2 * 33 + i] * fs[e * 33 + i];
        fs[600 + e * 17 + o2] = fmaxf(acc, 0.f);
    }
    __syncthreads();

    // ---- A8: logits ----
    if (t < 16) {
        float acc = be3[0];
        #pragma unroll
        for (int i = 0; i < 16; ++i) acc += We3[i] * fs[600 + t * 17 + i];
        out[t] = acc;
    }
    __syncthreads();

    // ---- GRU scan: wave 0 only ----
    if (t < 64) {
        const bool lowhalf = (t < 32);
        for (int e = 0; e < 16; ++e) {
            const int js = 2 * e, jd = 2 * e + 1;
            const int ss = fid_s[js], sd = fid_s[jd];
            const bool same = (nid_s[js] == nid_s[jd]);
            const int npass = same ? 2 : 1;
            for (int pass = 0; pass < npass; ++pass) {
                const bool do_src = (!same) || (pass == 0);
                const bool do_dst = (!same) || (pass == 1);
                float acc1 = b1, acc2 = b2, acc3 = b3;
                #pragma unroll
                for (int c = 0; c < 8; ++c) {
                    const float4 hs4 = *(const float4*)&slots[ss * 36 + 4 * c];
                    const float4 hd4 = *(const float4*)&slots[sd * 36 + 4 * c];
                    acc1 += dot4_(w1[c], hs4);
                    const float4 hm = lowhalf ? hs4 : hd4;
                    acc2 += dot4_(w2[c], hm);
                    acc3 += dot4_(w3[c], hd4);
                }
                const float shv = __shfl_xor(lowhalf ? acc3 : acc1, 32);
                const float hr = lowhalf ? acc1 : acc2;
                const float hz = shv;
                const float hn = lowhalf ? acc2 : acc3;
                const float ir  = gi_s[e * 97 + o];
                const float iz  = gi_s[e * 97 + 32 + o];
                const float inn = gi_s[e * 97 + 64 + o];
                const float r = sigmoidf_(ir + hr);
                const float z = sigmoidf_(iz + hz);
                const float nn = tanhf_(inn + r * hn);
                const int slot = lowhalf ? ss : sd;
                const float hold = slots[slot * 36 + o];
                const float hnew = (1.f - z) * nn + z * hold;
                const bool wr = lowhalf ? do_src : do_dst;
                if (wr) slots[slot * 36 + o] = hnew;
                __threadfence_block();
            }
        }
    }
    __syncthreads();

    // ---- writeback last occurrence of each node ----
    #pragma unroll
    for (int k = 0; k < 4; ++k) {
        int j2 = j0 + 8 * k;
        if (last_s[j2]) out[16 + nid_s[j2] * 32 + o] = slots[fid_s[j2] * 36 + o];
    }
}

// ---------------------------------------------------------------------------
extern "C" void kernel_launch(void* const* d_in, const int* in_sizes, int n_in,
                              void* d_out, int out_size, void* d_ws, size_t ws_size,
                              hipStream_t stream)
{
    (void)in_sizes; (void)n_in; (void)out_size; (void)ws_size;
    const int*   src   = (const int*)d_in[0];
    const int*   dst   = (const int*)d_in[1];
    const float* ef    = (const float*)d_in[2];
    const float* nf    = (const float*)d_in[4];
    const float* mem   = (const float*)d_in[6];
    const float* Wemb  = (const float*)d_in[7];
    const float* bemb  = (const float*)d_in[8];
    const float* Wqkv  = (const float*)d_in[9];
    const float* bqkv  = (const float*)d_in[10];
    const float* Wo    = (const float*)d_in[11];
    const float* bo    = (const float*)d_in[12];
    const float* g1    = (const float*)d_in[13];
    const float* be1   = (const float*)d_in[14];
    const float* g2    = (const float*)d_in[15];
    const float* be2   = (const float*)d_in[16];
    const float* Wf1   = (const float*)d_in[17];
    const float* bf1   = (const float*)d_in[18];
    const float* Wf2   = (const float*)d_in[19];
    const float* bf2   = (const float*)d_in[20];
    const float* Wscn  = (const float*)d_in[21];
    const float* bscn  = (const float*)d_in[22];
    const float* gscn  = (const float*)d_in[23];
    const float* bescn = (const float*)d_in[24];
    const float* We1   = (const float*)d_in[25];
    const float* be1e  = (const float*)d_in[26];
    const float* We2   = (const float*)d_in[27];
    const float* be2e  = (const float*)d_in[28];
    const float* We3   = (const float*)d_in[29];
    const float* be3   = (const float*)d_in[30];
    const float* Wih   = (const float*)d_in[31];
    const float* bih   = (const float*)d_in[32];
    const float* Whh   = (const float*)d_in[33];
    const float* bhh   = (const float*)d_in[34];
    const float* Wm1   = (const float*)d_in[35];
    const float* bm1   = (const float*)d_in[36];
    const float* Wm2   = (const float*)d_in[37];
    const float* bm2   = (const float*)d_in[38];
    float* out = (float*)d_out;
    float* ws  = (float*)d_ws;

    hipLaunchKernelGGL(k1_embed_qkv, dim3(257), dim3(256), 0, stream,
        nf, Wemb, bemb, Wqkv, bqkv, mem, src, dst, ef, Wm1, bm1, Wm2, bm2, Wih, bih, ws, out);
    hipLaunchKernelGGL(k2_attn, dim3(128), dim3(256), 0, stream, src, dst, ws);
    hipLaunchKernelGGL(k34_post_scan, dim3(1), dim3(256), 0, stream,
        src, dst, mem, Wo, bo, g1, be1, Wf1, bf1, Wf2, bf2, g2, be2,
        Wscn, bscn, gscn, bescn, Whh, bhh, We1, be1e, We2, be2e, We3, be3, ws, out);
}